// Round 1
// baseline (747.002 us; speedup 1.0000x reference)
//
#include <hip/hip_runtime.h>
#include <math.h>

#define B 64
#define S 2048
#define D 1024
#define H 300
#define NOUT 2
#define NCHUNK 16
#define CHUNK_S (S / NCHUNK) /* 128 */

static __device__ __forceinline__ int imin(int a, int b) { return a < b ? a : b; }

// ---------------------------------------------------------------------------
// Kernel 1: end_ind[b] = first s with input_ids[b,s]==1, fallback B (= shape[0])
// ---------------------------------------------------------------------------
__global__ void end_kernel(const int* __restrict__ ids, int* __restrict__ end_ind) {
    int b = blockIdx.x;
    int t = threadIdx.x;
    const int* row = ids + (size_t)b * S;
    int m = S;
    for (int s = t; s < S; s += 256) {
        if (row[s] == 1 && s < m) m = s;
    }
    __shared__ int red[256];
    red[t] = m;
    __syncthreads();
    for (int st = 128; st > 0; st >>= 1) {
        if (t < st) red[t] = imin(red[t], red[t + st]);
        __syncthreads();
    }
    if (t == 0) end_ind[b] = (red[0] < S) ? red[0] : B;
}

// ---------------------------------------------------------------------------
// Kernel 2a: deterministic partial sums. Block (chunk, b); thread t owns
// d = 4t..4t+3 (float4). Streams 128 s-rows, coalesced 16B/lane.
// ---------------------------------------------------------------------------
__global__ void sum_partial_kernel(const float* __restrict__ inputs,
                                   const float* __restrict__ drop,
                                   const int* __restrict__ end_ind,
                                   float* __restrict__ partial /* [B][NCHUNK][D] */) {
    int chunk = blockIdx.x;
    int b = blockIdx.y;
    int t = threadIdx.x;
    int e = end_ind[b];
    int s0 = chunk * CHUNK_S;
    int s1 = imin(s0 + CHUNK_S, e);
    int n = s1 - s0;

    float4 acc = make_float4(0.f, 0.f, 0.f, 0.f);
    __shared__ float w_lds[CHUNK_S];
    if (n > 0) {
        for (int i = t; i < n; i += 256) w_lds[i] = drop[(size_t)b * S + s0 + i];
        __syncthreads();
        const float4* p = (const float4*)(inputs + ((size_t)b * S + s0) * D) + t;
        for (int i = 0; i < n; ++i, p += D / 4) {
            float w = w_lds[i];
            float4 v = *p;
            acc.x = fmaf(v.x, w, acc.x);
            acc.y = fmaf(v.y, w, acc.y);
            acc.z = fmaf(v.z, w, acc.z);
            acc.w = fmaf(v.w, w, acc.w);
        }
    }
    // Every block writes (zeros for fully-skipped chunks) -> no memset needed.
    float4* op = (float4*)(partial + ((size_t)b * NCHUNK + chunk) * D) + t;
    *op = acc;
}

// ---------------------------------------------------------------------------
// Kernel 2b: atomic fallback if ws too small for partials (euph pre-zeroed)
// ---------------------------------------------------------------------------
__global__ void sum_atomic_kernel(const float* __restrict__ inputs,
                                  const float* __restrict__ drop,
                                  const int* __restrict__ end_ind,
                                  float* __restrict__ euph /* [B][D] zeroed */) {
    int chunk = blockIdx.x;
    int b = blockIdx.y;
    int t = threadIdx.x;
    int e = end_ind[b];
    int s0 = chunk * CHUNK_S;
    int s1 = imin(s0 + CHUNK_S, e);
    int n = s1 - s0;
    if (n <= 0) return;

    float4 acc = make_float4(0.f, 0.f, 0.f, 0.f);
    __shared__ float w_lds[CHUNK_S];
    for (int i = t; i < n; i += 256) w_lds[i] = drop[(size_t)b * S + s0 + i];
    __syncthreads();
    const float4* p = (const float4*)(inputs + ((size_t)b * S + s0) * D) + t;
    for (int i = 0; i < n; ++i, p += D / 4) {
        float w = w_lds[i];
        float4 v = *p;
        acc.x = fmaf(v.x, w, acc.x);
        acc.y = fmaf(v.y, w, acc.y);
        acc.z = fmaf(v.z, w, acc.z);
        acc.w = fmaf(v.w, w, acc.w);
    }
    float* dst = euph + (size_t)b * D + 4 * t;
    atomicAdd(dst + 0, acc.x);
    atomicAdd(dst + 1, acc.y);
    atomicAdd(dst + 2, acc.z);
    atomicAdd(dst + 3, acc.w);
}

// ---------------------------------------------------------------------------
// Kernel 3: per-batch-row MLP. Reduces nchunk partials -> x (LDS), then
// hidden = tanh(x @ W1^T + b1), out = hidden @ W2^T + b2.
// ---------------------------------------------------------------------------
__global__ void mlp_kernel(const float* __restrict__ partial, int nchunk,
                           const int* __restrict__ end_ind,
                           const float* __restrict__ W1, const float* __restrict__ b1,
                           const float* __restrict__ W2, const float* __restrict__ b2,
                           float* __restrict__ out) {
    int b = blockIdx.x;
    int t = threadIdx.x;
    __shared__ float4 x4[D / 4];     // 4 KB: euph row
    __shared__ float hidden[H];      // 1.2 KB
    __shared__ float red[256];

    float inv_e = 1.0f / (float)end_ind[b];
    {
        float4 a = make_float4(0.f, 0.f, 0.f, 0.f);
        const float4* p = (const float4*)(partial + (size_t)b * nchunk * D) + t;
        for (int c = 0; c < nchunk; ++c, p += D / 4) {
            float4 v = *p;
            a.x += v.x; a.y += v.y; a.z += v.z; a.w += v.w;
        }
        a.x *= inv_e; a.y *= inv_e; a.z *= inv_e; a.w *= inv_e;
        x4[t] = a;
    }
    __syncthreads();

    for (int h = t; h < H; h += 256) {
        const float4* w = (const float4*)(W1 + (size_t)h * D);
        float4 acc = make_float4(0.f, 0.f, 0.f, 0.f);
        for (int k = 0; k < D / 4; ++k) {
            float4 xv = x4[k];   // LDS broadcast (all lanes same addr -> free)
            float4 wv = w[k];
            acc.x = fmaf(xv.x, wv.x, acc.x);
            acc.y = fmaf(xv.y, wv.y, acc.y);
            acc.z = fmaf(xv.z, wv.z, acc.z);
            acc.w = fmaf(xv.w, wv.w, acc.w);
        }
        hidden[h] = tanhf(acc.x + acc.y + acc.z + acc.w + b1[h]);
    }
    __syncthreads();

    for (int o = 0; o < NOUT; ++o) {
        float p = 0.f;
        for (int h = t; h < H; h += 256) p += hidden[h] * W2[(size_t)o * H + h];
        red[t] = p;
        __syncthreads();
        for (int st = 128; st > 0; st >>= 1) {
            if (t < st) red[t] += red[t + st];
            __syncthreads();
        }
        if (t == 0) out[b * NOUT + o] = red[0] + b2[o];
        __syncthreads();
    }
}

// ---------------------------------------------------------------------------
extern "C" void kernel_launch(void* const* d_in, const int* in_sizes, int n_in,
                              void* d_out, int out_size, void* d_ws, size_t ws_size,
                              hipStream_t stream) {
    const float* inputs = (const float*)d_in[0];
    const int*   ids    = (const int*)d_in[1];
    const float* drop   = (const float*)d_in[2];
    const float* W1     = (const float*)d_in[3];
    const float* b1v    = (const float*)d_in[4];
    const float* W2     = (const float*)d_in[5];
    const float* b2v    = (const float*)d_in[6];
    float* out = (float*)d_out;

    // ws layout: [0,256): end_ind (64 ints, padded); [256, ...): partials
    int*   end_ind = (int*)d_ws;
    float* partial = (float*)((char*)d_ws + 256);
    const size_t need = 256 + (size_t)B * NCHUNK * D * sizeof(float);

    end_kernel<<<B, 256, 0, stream>>>(ids, end_ind);

    if (ws_size >= need) {
        sum_partial_kernel<<<dim3(NCHUNK, B), 256, 0, stream>>>(inputs, drop, end_ind, partial);
        mlp_kernel<<<B, 256, 0, stream>>>(partial, NCHUNK, end_ind, W1, b1v, W2, b2v, out);
    } else {
        hipMemsetAsync(partial, 0, (size_t)B * D * sizeof(float), stream);
        sum_atomic_kernel<<<dim3(NCHUNK, B), 256, 0, stream>>>(inputs, drop, end_ind, partial);
        mlp_kernel<<<B, 256, 0, stream>>>(partial, 1, end_ind, W1, b1v, W2, b2v, out);
    }
}

// Round 3
// 692.363 us; speedup vs baseline: 1.0789x; 1.0789x over previous
//
#include <hip/hip_runtime.h>
#include <math.h>

#define B 64
#define S 2048
#define D 1024
#define H 300
#define NOUT 2
#define NCHUNK 16
#define CHUNK_S (S / NCHUNK) /* 128 */

typedef float fx4 __attribute__((ext_vector_type(4)));  // native vector: works with nontemporal builtins

static __device__ __forceinline__ int imin(int a, int b) { return a < b ? a : b; }

// ---------------------------------------------------------------------------
// Kernel 1: end_ind[b] = first s with input_ids[b,s]==1, fallback B (= shape[0])
// ---------------------------------------------------------------------------
__global__ __launch_bounds__(256) void end_kernel(const int* __restrict__ ids,
                                                  int* __restrict__ end_ind) {
    int b = blockIdx.x;
    int t = threadIdx.x;
    const int* row = ids + (size_t)b * S;
    int m = S;
    for (int s = t; s < S; s += 256) {
        if (row[s] == 1 && s < m) m = s;
    }
    __shared__ int red[256];
    red[t] = m;
    __syncthreads();
    for (int st = 128; st > 0; st >>= 1) {
        if (t < st) red[t] = imin(red[t], red[t + st]);
        __syncthreads();
    }
    if (t == 0) end_ind[b] = (red[0] < S) ? red[0] : B;
}

// ---------------------------------------------------------------------------
// Kernel 2: deterministic partial sums. Block (chunk, b); thread t owns
// d = 4t..4t+3 (fx4). Manual 4-row unroll -> 4 independent nontemporal
// 16B loads in flight per thread (inputs are read-once: bypass L2 retention).
// ---------------------------------------------------------------------------
__global__ __launch_bounds__(256) void sum_partial_kernel(
        const float* __restrict__ inputs,
        const float* __restrict__ drop,
        const int* __restrict__ end_ind,
        float* __restrict__ partial /* [B][NCHUNK][D] */) {
    int chunk = blockIdx.x;
    int b = blockIdx.y;
    int t = threadIdx.x;
    int e = end_ind[b];
    int s0 = chunk * CHUNK_S;
    int s1 = imin(s0 + CHUNK_S, e);
    int n = s1 - s0;

    fx4 a0 = (fx4)(0.f);
    fx4 a1 = a0, a2 = a0, a3 = a0;
    __shared__ float w_lds[CHUNK_S];

    if (n > 0) {
        if (t < CHUNK_S) {
            w_lds[t] = (t < n) ? drop[(size_t)b * S + s0 + t] : 0.f;
        }
        __syncthreads();
        const fx4* p = (const fx4*)(inputs + ((size_t)b * S + s0) * D) + t;
        const int R = D / 4; // fx4s per row
        int i = 0;
        for (; i + 4 <= n; i += 4, p += 4 * R) {
            fx4 v0 = __builtin_nontemporal_load(p + 0 * R);
            fx4 v1 = __builtin_nontemporal_load(p + 1 * R);
            fx4 v2 = __builtin_nontemporal_load(p + 2 * R);
            fx4 v3 = __builtin_nontemporal_load(p + 3 * R);
            a0 += v0 * w_lds[i + 0];
            a1 += v1 * w_lds[i + 1];
            a2 += v2 * w_lds[i + 2];
            a3 += v3 * w_lds[i + 3];
        }
        for (; i < n; ++i, p += R) {
            fx4 v = __builtin_nontemporal_load(p);
            a0 += v * w_lds[i];
        }
        a0 += (a1 + a2) + a3;
    }
    // Every block writes (zeros for fully-skipped chunks) -> no memset needed.
    fx4* op = (fx4*)(partial + ((size_t)b * NCHUNK + chunk) * D) + t;
    *op = a0;
}

// ---------------------------------------------------------------------------
// Kernel 3: per-batch-row MLP. Reduces NCHUNK partials -> x (LDS), then
// hidden = tanh(x @ W1^T + b1), out = hidden @ W2^T + b2.
// ---------------------------------------------------------------------------
__global__ __launch_bounds__(256) void mlp_kernel(
        const float* __restrict__ partial,
        const int* __restrict__ end_ind,
        const float* __restrict__ W1, const float* __restrict__ b1,
        const float* __restrict__ W2, const float* __restrict__ b2,
        float* __restrict__ out) {
    int b = blockIdx.x;
    int t = threadIdx.x;
    __shared__ fx4 x4[D / 4];        // 4 KB: euph row
    __shared__ float hidden[H];      // 1.2 KB
    __shared__ float red[256];

    float inv_e = 1.0f / (float)end_ind[b];
    {
        fx4 a = (fx4)(0.f);
        const fx4* p = (const fx4*)(partial + (size_t)b * NCHUNK * D) + t;
        for (int c = 0; c < NCHUNK; ++c, p += D / 4) {
            a += p[0];
        }
        x4[t] = a * inv_e;
    }
    __syncthreads();

    for (int h = t; h < H; h += 256) {
        const fx4* w = (const fx4*)(W1 + (size_t)h * D);
        fx4 acc = (fx4)(0.f);
        for (int k = 0; k < D / 4; ++k) {
            acc += x4[k] * w[k];   // LDS broadcast (same addr across lanes -> free)
        }
        hidden[h] = tanhf(acc.x + acc.y + acc.z + acc.w + b1[h]);
    }
    __syncthreads();

    for (int o = 0; o < NOUT; ++o) {
        float p = 0.f;
        for (int h = t; h < H; h += 256) p += hidden[h] * W2[(size_t)o * H + h];
        red[t] = p;
        __syncthreads();
        for (int st = 128; st > 0; st >>= 1) {
            if (t < st) red[t] += red[t + st];
            __syncthreads();
        }
        if (t == 0) out[b * NOUT + o] = red[0] + b2[o];
        __syncthreads();
    }
}

// ---------------------------------------------------------------------------
extern "C" void kernel_launch(void* const* d_in, const int* in_sizes, int n_in,
                              void* d_out, int out_size, void* d_ws, size_t ws_size,
                              hipStream_t stream) {
    const float* inputs = (const float*)d_in[0];
    const int*   ids    = (const int*)d_in[1];
    const float* drop   = (const float*)d_in[2];
    const float* W1     = (const float*)d_in[3];
    const float* b1v    = (const float*)d_in[4];
    const float* W2     = (const float*)d_in[5];
    const float* b2v    = (const float*)d_in[6];
    float* out = (float*)d_out;

    // ws layout: [0,256): end_ind (64 ints, padded); [256, ...): partials
    int*   end_ind = (int*)d_ws;
    float* partial = (float*)((char*)d_ws + 256);

    end_kernel<<<B, 256, 0, stream>>>(ids, end_ind);
    sum_partial_kernel<<<dim3(NCHUNK, B), 256, 0, stream>>>(inputs, drop, end_ind, partial);
    mlp_kernel<<<B, 256, 0, stream>>>(partial, end_ind, W1, b1v, W2, b2v, out);
}